// Round 9
// baseline (1298.430 us; speedup 1.0000x reference)
//
#include <hip/hip_runtime.h>
#include <hip/hip_cooperative_groups.h>

namespace cg = cooperative_groups;

static constexpr int N_NODES = 100000;
static constexpr int N_EDGES = 3200000;
static constexpr int IN_CH = 512;
static constexpr int H = 16;
static constexpr int TB = 256;

static constexpr int BN = 256;                       // nodes per bucket
static constexpr int NB = (N_NODES + BN - 1) / BN;   // 391 buckets
static constexpr int CAP = 8960;                     // ebuf slots/bucket
static constexpr int CAP2 = CAP + 3 * BN;            // 9728 sorted+padded slots
static constexpr int CHUNK = 1536;                   // edges per scatter chunk
static constexpr int GRID_SC = (N_EDGES + CHUNK - 1) / CHUNK;  // 2084
static constexpr int NBLK64 = (N_NODES + 63) / 64;   // 1563 gather blocks

// Single fused pipeline kernel at FULL occupancy (8 blocks/CU target).
// Phases separated by grid.sync():
// P0 init cursors | P1 chunked scatter | P2 bucket counting sort
// P3 X@W1*dn -> hA | P4 gather+relu+16x16+dn -> hB | P5 gather+relu+16x1+dn -> hs3
// P6 final 1-ch gather -> out
__global__ __launch_bounds__(TB, 8) void k_fused(
    const float* __restrict__ x, const int* __restrict__ ei,
    const float* __restrict__ W1, const float* __restrict__ b1,
    const float* __restrict__ W2, const float* __restrict__ b2,
    const float* __restrict__ W3, const float* __restrict__ b3,
    float* __restrict__ out,
    int* __restrict__ ebuf, int* __restrict__ ebuf2, int* __restrict__ gcur,
    int* __restrict__ nrs, int* __restrict__ nend, float* __restrict__ disq,
    float* __restrict__ hA, float* __restrict__ hB, float* __restrict__ hs3) {
  cg::grid_group grid = cg::this_grid();
  __shared__ int scnt[NB];     // P1 cnt / P2 cnt (first 256)
  __shared__ int sofs[NB];     // P1 gofs / P2 prefix
  __shared__ int cur2[BN];     // P2 bump cursors
  __shared__ float agg[64 * 20];  // P4 (stride 20 kills bank conflicts)
  __shared__ float w[256];     // P4 W2
  int t = threadIdx.x;
  int wg = blockIdx.x, nwg = gridDim.x;
  int gid = wg * TB + t;
  int nthr = nwg * TB;

  // ---- P0: bump cursors into fixed-capacity bucket regions ----
  for (int b = gid; b < NB; b += nthr) gcur[b] = b * CAP;
  grid.sync();

  // ---- P1: chunked reserve-then-write scatter (contiguous run per (chunk,bucket)) ----
  for (int c = wg; c < GRID_SC; c += nwg) {
    int c0 = c * CHUNK, c1 = min(c0 + CHUNK, N_EDGES);
    for (int b = t; b < NB; b += TB) scnt[b] = 0;
    __syncthreads();
    for (int j = c0 + t; j < c1; j += TB) atomicAdd(&scnt[ei[N_EDGES + j] >> 8], 1);
    __syncthreads();
    for (int b = t; b < NB; b += TB)
      if (scnt[b] > 0) sofs[b] = atomicAdd(&gcur[b], scnt[b]);
    __syncthreads();
    for (int j = c0 + t; j < c1; j += TB) {
      int s = ei[j];
      int d = ei[N_EDGES + j];
      int slot = atomicAdd(&sofs[d >> 8], 1);
      ebuf[slot] = ((d & 255) << 17) | s;  // pack dst-low | src
    }
    __syncthreads();
  }
  grid.sync();

  // ---- P2: per-bucket counting sort, 4-aligned runs, pads -> dummy node N ----
  for (int b = wg; b < NB; b += nwg) {
    scnt[t] = 0;
    __syncthreads();
    int beg = b * CAP, end = gcur[b];
    for (int j = beg + t; j < end; j += TB) atomicAdd(&scnt[ebuf[j] >> 17], 1);
    __syncthreads();
    int myc = scnt[t];
    int ac = (myc + 3) & ~3;
    sofs[t] = ac;
    __syncthreads();
    for (int off = 1; off < TB; off <<= 1) {
      int v = (t >= off) ? sofs[t - off] : 0;
      __syncthreads();
      sofs[t] += v;
      __syncthreads();
    }
    int start = b * CAP2 + ((t == 0) ? 0 : sofs[t - 1]);
    cur2[t] = start;
    int node = b * BN + t;
    if (node < N_NODES) {
      nrs[node] = start;
      nend[node] = start + ac;
      disq[node] = 1.0f / sqrtf((float)myc + 1.0f);
      for (int j = start + myc; j < start + ac; j++) ebuf2[j] = N_NODES;
    }
    __syncthreads();
    for (int j = beg + t; j < end; j += TB) {
      int p = ebuf[j];
      int slot = atomicAdd(&cur2[p >> 17], 1);
      ebuf2[slot] = p & 0x1FFFF;
    }
    __syncthreads();
  }
  grid.sync();

  // ---- P3: hA[r][0..15] = (X@W1)[r]*disq[r], interleaved 64B rows; dummy row N ----
  for (int r = gid; r <= N_NODES; r += nthr) {
    float4* oa = (float4*)(hA + (size_t)r * 16);
    if (r == N_NODES) {
      float4 z = make_float4(0.f, 0.f, 0.f, 0.f);
      float4* ob = (float4*)(hB + (size_t)r * 16);
#pragma unroll
      for (int i = 0; i < 4; i++) { oa[i] = z; ob[i] = z; }
      hs3[r] = 0.f;
      continue;
    }
    const float4* xr = (const float4*)(x + (size_t)r * IN_CH);
    float acc[H];
#pragma unroll
    for (int c = 0; c < H; c++) acc[c] = 0.f;
    for (int k4 = 0; k4 < IN_CH / 4; k4++) {
      float4 xv = xr[k4];
      const float* wr = W1 + k4 * 4 * H;
      float xs[4] = {xv.x, xv.y, xv.z, xv.w};
#pragma unroll
      for (int j = 0; j < 4; j++) {
#pragma unroll
        for (int c = 0; c < H; c++) acc[c] = fmaf(xs[j], wr[j * H + c], acc[c]);
      }
    }
    float dn = disq[r];
    oa[0] = make_float4(acc[0] * dn, acc[1] * dn, acc[2] * dn, acc[3] * dn);
    oa[1] = make_float4(acc[4] * dn, acc[5] * dn, acc[6] * dn, acc[7] * dn);
    oa[2] = make_float4(acc[8] * dn, acc[9] * dn, acc[10] * dn, acc[11] * dn);
    oa[3] = make_float4(acc[12] * dn, acc[13] * dn, acc[14] * dn, acc[15] * dn);
  }
  grid.sync();

  // ---- P4: gather(hA) + relu + 16x16 GEMM + dn -> hB. 4 lanes/node, float4/lane ----
  w[t] = W2[t];
  {
    int nl = t >> 2, q = t & 3;
    const float4* h4 = (const float4*)hA;
    for (int blk = wg; blk < NBLK64; blk += nwg) {
      int node = blk * 64 + nl;
      if (node < N_NODES) {
        int beg = nrs[node], endp = nend[node];
        float4 acc = make_float4(0.f, 0.f, 0.f, 0.f);
        for (int j = beg; j < endp; j += 4) {
          int4 s = *(const int4*)(ebuf2 + j);
          float4 a0 = h4[s.x * 4 + q];
          float4 a1 = h4[s.y * 4 + q];
          float4 a2 = h4[s.z * 4 + q];
          float4 a3 = h4[s.w * 4 + q];
          acc.x += (a0.x + a1.x) + (a2.x + a3.x);
          acc.y += (a0.y + a1.y) + (a2.y + a3.y);
          acc.z += (a0.z + a1.z) + (a2.z + a3.z);
          acc.w += (a0.w + a1.w) + (a2.w + a3.w);
        }
        float4 sf = h4[node * 4 + q];
        float dn = disq[node];
        float4 bi = *(const float4*)(b1 + q * 4);
        float4 r;
        r.x = fmaf(acc.x + sf.x, dn, bi.x);
        r.y = fmaf(acc.y + sf.y, dn, bi.y);
        r.z = fmaf(acc.z + sf.z, dn, bi.z);
        r.w = fmaf(acc.w + sf.w, dn, bi.w);
        *(float4*)(agg + nl * 20 + q * 4) = r;
      }
      __syncthreads();
      if (node < N_NODES) {
        float o0 = 0.f, o1 = 0.f, o2 = 0.f, o3 = 0.f;
#pragma unroll
        for (int c4 = 0; c4 < 4; c4++) {
          float4 av = *(const float4*)(agg + nl * 20 + c4 * 4);
          float vs[4] = {av.x, av.y, av.z, av.w};
#pragma unroll
          for (int i2 = 0; i2 < 4; i2++) {
            float v = fmaxf(vs[i2], 0.f);
            const float* wr = w + (c4 * 4 + i2) * 16 + q * 4;
            o0 = fmaf(v, wr[0], o0);
            o1 = fmaf(v, wr[1], o1);
            o2 = fmaf(v, wr[2], o2);
            o3 = fmaf(v, wr[3], o3);
          }
        }
        float dn = disq[node];
        *(float4*)(hB + (size_t)node * 16 + q * 4) =
            make_float4(o0 * dn, o1 * dn, o2 * dn, o3 * dn);
      }
      __syncthreads();
    }
  }
  grid.sync();

  // ---- P5: gather(hB) + relu + 16x1 + dn -> hs3. No LDS; 4-lane shfl reduce ----
  {
    int nl = t >> 2, q = t & 3;
    const float4* h4 = (const float4*)hB;
    float4 w3v = *(const float4*)(W3 + q * 4);
    float4 bi = *(const float4*)(b2 + q * 4);
    for (int blk = wg; blk < NBLK64; blk += nwg) {
      int node = blk * 64 + nl;
      if (node < N_NODES) {
        int beg = nrs[node], endp = nend[node];
        float4 acc = make_float4(0.f, 0.f, 0.f, 0.f);
        for (int j = beg; j < endp; j += 4) {
          int4 s = *(const int4*)(ebuf2 + j);
          float4 a0 = h4[s.x * 4 + q];
          float4 a1 = h4[s.y * 4 + q];
          float4 a2 = h4[s.z * 4 + q];
          float4 a3 = h4[s.w * 4 + q];
          acc.x += (a0.x + a1.x) + (a2.x + a3.x);
          acc.y += (a0.y + a1.y) + (a2.y + a3.y);
          acc.z += (a0.z + a1.z) + (a2.z + a3.z);
          acc.w += (a0.w + a1.w) + (a2.w + a3.w);
        }
        float4 sf = h4[node * 4 + q];
        float dn = disq[node];
        float v0 = fmaxf(fmaf(acc.x + sf.x, dn, bi.x), 0.f);
        float v1 = fmaxf(fmaf(acc.y + sf.y, dn, bi.y), 0.f);
        float v2 = fmaxf(fmaf(acc.z + sf.z, dn, bi.z), 0.f);
        float v3 = fmaxf(fmaf(acc.w + sf.w, dn, bi.w), 0.f);
        float o = v0 * w3v.x;
        o = fmaf(v1, w3v.y, o);
        o = fmaf(v2, w3v.z, o);
        o = fmaf(v3, w3v.w, o);
        o += __shfl_xor(o, 1);
        o += __shfl_xor(o, 2);
        if (q == 0) hs3[node] = o * dn;
      }
    }
  }
  grid.sync();

  // ---- P6: final 1-channel gather -> out ----
  {
    int nl = t >> 2, lane = t & 3;
    float b3v = b3[0];
    for (int blk = wg; blk < NBLK64; blk += nwg) {
      int node = blk * 64 + nl;
      if (node < N_NODES) {
        int beg = nrs[node], endp = nend[node];
        float acc = 0.f;
        for (int j = beg + 4 * lane; j < endp; j += 16) {
          int4 s = *(const int4*)(ebuf2 + j);
          acc += (hs3[s.x] + hs3[s.y]) + (hs3[s.z] + hs3[s.w]);
        }
        acc += __shfl_xor(acc, 1);
        acc += __shfl_xor(acc, 2);
        if (lane == 0) out[node] = fmaf(acc + hs3[node], disq[node], b3v);
      }
    }
  }
}

extern "C" void kernel_launch(void* const* d_in, const int* in_sizes, int n_in,
                              void* d_out, int out_size, void* d_ws, size_t ws_size,
                              hipStream_t stream) {
  const float* x = (const float*)d_in[0];
  const int* ei = (const int*)d_in[1];  // integer inputs delivered as int32
  const float* W1 = (const float*)d_in[2];
  const float* b1 = (const float*)d_in[3];
  const float* W2 = (const float*)d_in[4];
  const float* b2 = (const float*)d_in[5];
  const float* W3 = (const float*)d_in[6];
  const float* b3 = (const float*)d_in[7];
  float* out = (float*)d_out;

  // Workspace (~52 MB), 16B-aligned segments.
  int* ebuf = (int*)d_ws;                        // NB*CAP (14.0 MB)
  int* ebuf2 = ebuf + (size_t)NB * CAP;          // NB*CAP2 (15.2 MB)
  int* gcur = ebuf2 + (size_t)NB * CAP2;         // NB
  int* nrs = gcur + NB;                          // N
  int* nend = nrs + N_NODES;                     // N
  int pad = (4 - ((NB + 2 * N_NODES) & 3)) & 3;  // realign to 16B
  float* disq = (float*)(nend + N_NODES + pad);  // N
  float* hA = disq + N_NODES;                    // 16*(N+1) interleaved rows
  float* hB = hA + (size_t)(N_NODES + 1) * 16;   // 16*(N+1)
  float* hs3 = hB + (size_t)(N_NODES + 1) * 16;  // N+1

  // Cooperative grid at FULL occupancy: 8 blocks/CU x 256 CUs = 2048 WGs
  // (R6 ran 782 -> 37% occupancy and was latency-bound; this is the fix).
  static int grid = 0;
  if (grid == 0) {
    int nb = 0;
    (void)hipOccupancyMaxActiveBlocksPerMultiprocessor(&nb, k_fused, TB, 0);
    if (nb < 1) nb = 1;
    int cap = nb * 256;  // 256 CUs on MI355X
    grid = cap < 2048 ? cap : 2048;
  }

  void* args[] = {(void*)&x,  (void*)&ei,  (void*)&W1, (void*)&b1, (void*)&W2,
                  (void*)&b2, (void*)&W3,  (void*)&b3, (void*)&out, (void*)&ebuf,
                  (void*)&ebuf2, (void*)&gcur, (void*)&nrs, (void*)&nend,
                  (void*)&disq, (void*)&hA, (void*)&hB, (void*)&hs3};
  hipLaunchCooperativeKernel((void*)k_fused, dim3(grid), dim3(TB), args, 0, stream);
}